// Round 4
// baseline (1234.437 us; speedup 1.0000x reference)
//
#include <hip/hip_runtime.h>
#include <math.h>

#define NN 50000
#define NE 800000
#define TT 6
#define HID 48
#define NB 196   // (NN+255)/256

__device__ __forceinline__ float sigmoidf_(float x){ return 1.0f/(1.0f+__expf(-x)); }
__device__ __forceinline__ unsigned f2bf(float x){
  unsigned u = __float_as_uint(x);
  return (u + 0x7fffu + ((u>>16)&1u)) >> 16;   // RNE to bf16
}
__device__ __forceinline__ unsigned pack2(float a, float b){
  return f2bf(a) | (f2bf(b)<<16);
}
__device__ __forceinline__ float bflo(unsigned u){ return __uint_as_float(u<<16); }
__device__ __forceinline__ float bfhi(unsigned u){ return __uint_as_float(u & 0xffff0000u); }

struct U3 { unsigned x,y,z; };

// 256-thread inclusive block scan (4 waves of 64)
__device__ __forceinline__ int block_scan_incl(int x, int* wsum){
  int lane = threadIdx.x & 63, w = threadIdx.x >> 6;
  int v = x;
#pragma unroll
  for(int d=1; d<64; d<<=1){
    int u = __shfl_up(v, d, 64);
    if(lane >= d) v += u;
  }
  if(lane==63) wsum[w] = v;
  __syncthreads();
  int add = 0;
#pragma unroll
  for(int k=0;k<3;k++) if(w>k) add += wsum[k];
  return v + add;
}

// ---------------- setup ----------------
__global__ __launch_bounds__(256) void k_setup(float* deg, int* cnt,
                                               const float* __restrict__ Wih, const float* __restrict__ Whh,
                                               float* WihT, float* WhhT){
  int i = blockIdx.x*256+threadIdx.x;
  if(i<NN){ deg[i]=1.0f; cnt[i]=0; }          // self-loop weight 1 pre-added
  if(i<144*HID){ int o=i/HID, k=i%HID; WihT[k*144+o]=Wih[i]; WhhT[k*144+o]=Whh[i]; }
}

__global__ __launch_bounds__(256) void k_degcnt(const int* __restrict__ ei, const float* __restrict__ ew,
                                                float* deg, int* cnt){
  int e = blockIdx.x*256+threadIdx.x;
  if(e<NE){
    int c = ei[NE+e];
    atomicAdd(&deg[c], ew[e]);
    atomicAdd(&cnt[c], 1);
  }
}

// phase A: per-block sums of cnt, plus dis = rsqrt(deg)
__global__ __launch_bounds__(256) void k_partA(const int* __restrict__ cnt, const float* __restrict__ deg,
                                               float* dis, int* bsum){
  __shared__ int wsum[4];
  int i = blockIdx.x*256+threadIdx.x;
  int x = 0;
  if(i<NN){
    x = cnt[i];
    float d = deg[i];
    dis[i] = d>0.f ? rsqrtf(fmaxf(d,1e-12f)) : 0.f;
  }
  int lane = threadIdx.x & 63, w = threadIdx.x >> 6;
  int v = x;
#pragma unroll
  for(int m=32;m>=1;m>>=1) v += __shfl_xor(v, m, 64);
  if(lane==0) wsum[w]=v;
  __syncthreads();
  if(threadIdx.x==0) bsum[blockIdx.x] = wsum[0]+wsum[1]+wsum[2]+wsum[3];
}

// phase B: exclusive scan of 196 block sums
__global__ __launch_bounds__(256) void k_midB(const int* __restrict__ bsum, int* bpre, int* offs){
  __shared__ int wsum[4];
  int t = threadIdx.x;
  int x = (t<NB)? bsum[t] : 0;
  int incl = block_scan_incl(x, wsum);
  if(t<NB) bpre[t] = incl - x;
  if(t==255) offs[NN] = incl;   // total
}

// phase C: per-block exclusive scan of cnt + bpre -> offs/cursor
__global__ __launch_bounds__(256) void k_offsC(const int* __restrict__ cnt, const int* __restrict__ bpre,
                                               int* offs, int* cursor){
  __shared__ int wsum[4];
  int i = blockIdx.x*256+threadIdx.x;
  int x = (i<NN)? cnt[i] : 0;
  int incl = block_scan_incl(x, wsum);
  int val = bpre[blockIdx.x] + incl - x;
  if(i<NN){ offs[i]=val; cursor[i]=val; }
}

__global__ __launch_bounds__(256) void k_scatter(const int* __restrict__ ei, const float* __restrict__ ew,
                                                 const float* __restrict__ dis, int* cursor,
                                                 int2* __restrict__ csr){
  int e = blockIdx.x*256+threadIdx.x;
  if(e<NE){
    int r=ei[e], c=ei[NE+e];
    int pos=atomicAdd(&cursor[c],1);
    int2 v; v.x=r; v.y=__float_as_int(dis[r]*ew[e]*dis[c]);
    csr[pos]=v;
  }
}

// ---------------- layer-0 matmul, all 6 t per thread, bf16 [f][t6] 12B/feature output ----------------
__global__ __launch_bounds__(256) void k_mm0(const float* __restrict__ X, const float* __restrict__ W,
                                             unsigned* __restrict__ A){
  int tid = blockIdx.x*256+threadIdx.x;
  int n = tid>>2, s = tid&3;
  if(n>=NN) return;
  const float* xb = X + (long long)n*64;
  const float* wb = W + 12*s;
  float acc[TT][12];
#pragma unroll
  for(int t=0;t<TT;t++)
#pragma unroll
    for(int j=0;j<12;j++) acc[t][j]=0.f;
#pragma unroll 2
  for(int k4=0;k4<16;k4++){
    float4 xv[TT];
#pragma unroll
    for(int t=0;t<TT;t++) xv[t] = *reinterpret_cast<const float4*>(xb + (long long)t*NN*64 + 4*k4);
#pragma unroll
    for(int q=0;q<4;q++){
      const float* wr = wb + (4*k4+q)*HID;
      float w[12];
#pragma unroll
      for(int j=0;j<12;j++) w[j]=wr[j];
#pragma unroll
      for(int t=0;t<TT;t++){
        float xs = (&xv[t].x)[q];
#pragma unroll
        for(int j=0;j<12;j++) acc[t][j] = fmaf(xs, w[j], acc[t][j]);
      }
    }
  }
  unsigned buf[36];
#pragma unroll
  for(int j=0;j<12;j++){
    buf[3*j  ]=pack2(acc[0][j],acc[1][j]);
    buf[3*j+1]=pack2(acc[2][j],acc[3][j]);
    buf[3*j+2]=pack2(acc[4][j],acc[5][j]);
  }
  uint4* o4 = reinterpret_cast<uint4*>(A + (long long)n*144 + 36*s);
#pragma unroll
  for(int q=0;q<9;q++) o4[q] = make_uint4(buf[4*q],buf[4*q+1],buf[4*q+2],buf[4*q+3]);
}

// ---------------- layer-1 matmul (K=48), input fp32 [n][t][48] ----------------
__global__ __launch_bounds__(256) void k_mm1(const float* __restrict__ X, const float* __restrict__ W,
                                             unsigned* __restrict__ A){
  int tid = blockIdx.x*256+threadIdx.x;
  int n = tid>>2, s = tid&3;
  if(n>=NN) return;
  const float* xb = X + (long long)n*(TT*HID);
  const float* wb = W + 12*s;
  float acc[TT][12];
#pragma unroll
  for(int t=0;t<TT;t++)
#pragma unroll
    for(int j=0;j<12;j++) acc[t][j]=0.f;
#pragma unroll 2
  for(int k4=0;k4<12;k4++){
    float4 xv[TT];
#pragma unroll
    for(int t=0;t<TT;t++) xv[t] = *reinterpret_cast<const float4*>(xb + t*HID + 4*k4);
#pragma unroll
    for(int q=0;q<4;q++){
      const float* wr = wb + (4*k4+q)*HID;
      float w[12];
#pragma unroll
      for(int j=0;j<12;j++) w[j]=wr[j];
#pragma unroll
      for(int t=0;t<TT;t++){
        float xs = (&xv[t].x)[q];
#pragma unroll
        for(int j=0;j<12;j++) acc[t][j] = fmaf(xs, w[j], acc[t][j]);
      }
    }
  }
  unsigned buf[36];
#pragma unroll
  for(int j=0;j<12;j++){
    buf[3*j  ]=pack2(acc[0][j],acc[1][j]);
    buf[3*j+1]=pack2(acc[2][j],acc[3][j]);
    buf[3*j+2]=pack2(acc[4][j],acc[5][j]);
  }
  uint4* o4 = reinterpret_cast<uint4*>(A + (long long)n*144 + 36*s);
#pragma unroll
  for(int q=0;q<9;q++) o4[q] = make_uint4(buf[4*q],buf[4*q+1],buf[4*q+2],buf[4*q+3]);
}

// ---------------- CSR aggregation (bf16 gather, 12B/edge-feature) + bias + LN + ReLU (+resid)
__global__ __launch_bounds__(256) void k_agg(const unsigned* __restrict__ A, const float* __restrict__ bias,
                                             const float* __restrict__ gain, const float* __restrict__ beta,
                                             const float* __restrict__ resid, float* __restrict__ out,
                                             const int* __restrict__ offs, const int2* __restrict__ csr,
                                             const float* __restrict__ dis){
  int wid = (blockIdx.x*256+threadIdx.x)>>6;
  int lane = threadIdx.x & 63;
  if(wid>=NN) return;
  const bool act = lane<HID;
  const int f = act? lane : (HID-1);
  float dn = dis[wid];
  float sw = dn*dn;
  float acc[TT];
  {
    U3 v = *reinterpret_cast<const U3*>(A + (long long)wid*144 + 3*f);
    acc[0]=sw*bflo(v.x); acc[1]=sw*bfhi(v.x);
    acc[2]=sw*bflo(v.y); acc[3]=sw*bfhi(v.y);
    acc[4]=sw*bflo(v.z); acc[5]=sw*bfhi(v.z);
  }
  int e0=offs[wid], e1=offs[wid+1];
  int e=e0;
  for(; e+3<e1; e+=4){
    int2 i0=csr[e], i1=csr[e+1], i2=csr[e+2], i3=csr[e+3];
    U3 d0 = *reinterpret_cast<const U3*>(A + (long long)i0.x*144 + 3*f);
    U3 d1 = *reinterpret_cast<const U3*>(A + (long long)i1.x*144 + 3*f);
    U3 d2 = *reinterpret_cast<const U3*>(A + (long long)i2.x*144 + 3*f);
    U3 d3 = *reinterpret_cast<const U3*>(A + (long long)i3.x*144 + 3*f);
    float n0=__int_as_float(i0.y), n1=__int_as_float(i1.y);
    float n2=__int_as_float(i2.y), n3=__int_as_float(i3.y);
    acc[0]=fmaf(n0,bflo(d0.x),acc[0]); acc[1]=fmaf(n0,bfhi(d0.x),acc[1]);
    acc[2]=fmaf(n0,bflo(d0.y),acc[2]); acc[3]=fmaf(n0,bfhi(d0.y),acc[3]);
    acc[4]=fmaf(n0,bflo(d0.z),acc[4]); acc[5]=fmaf(n0,bfhi(d0.z),acc[5]);
    acc[0]=fmaf(n1,bflo(d1.x),acc[0]); acc[1]=fmaf(n1,bfhi(d1.x),acc[1]);
    acc[2]=fmaf(n1,bflo(d1.y),acc[2]); acc[3]=fmaf(n1,bfhi(d1.y),acc[3]);
    acc[4]=fmaf(n1,bflo(d1.z),acc[4]); acc[5]=fmaf(n1,bfhi(d1.z),acc[5]);
    acc[0]=fmaf(n2,bflo(d2.x),acc[0]); acc[1]=fmaf(n2,bfhi(d2.x),acc[1]);
    acc[2]=fmaf(n2,bflo(d2.y),acc[2]); acc[3]=fmaf(n2,bfhi(d2.y),acc[3]);
    acc[4]=fmaf(n2,bflo(d2.z),acc[4]); acc[5]=fmaf(n2,bfhi(d2.z),acc[5]);
    acc[0]=fmaf(n3,bflo(d3.x),acc[0]); acc[1]=fmaf(n3,bfhi(d3.x),acc[1]);
    acc[2]=fmaf(n3,bflo(d3.y),acc[2]); acc[3]=fmaf(n3,bfhi(d3.y),acc[3]);
    acc[4]=fmaf(n3,bflo(d3.z),acc[4]); acc[5]=fmaf(n3,bfhi(d3.z),acc[5]);
  }
  for(; e<e1; ++e){
    int2 i0=csr[e];
    U3 d0 = *reinterpret_cast<const U3*>(A + (long long)i0.x*144 + 3*f);
    float n0=__int_as_float(i0.y);
    acc[0]=fmaf(n0,bflo(d0.x),acc[0]); acc[1]=fmaf(n0,bfhi(d0.x),acc[1]);
    acc[2]=fmaf(n0,bflo(d0.y),acc[2]); acc[3]=fmaf(n0,bfhi(d0.y),acc[3]);
    acc[4]=fmaf(n0,bflo(d0.z),acc[4]); acc[5]=fmaf(n0,bfhi(d0.z),acc[5]);
  }
  float bb = bias[f], gg = gain[f], be = beta[f];
  const float rn = 1.0f/HID;
#pragma unroll
  for(int t=0;t<TT;t++){
    float val = acc[t] + bb;
    float v = act? val : 0.f;
    float s = v, s2 = v*v;
#pragma unroll
    for(int m=32;m>=1;m>>=1){
      s  += __shfl_xor(s,  m, 64);
      s2 += __shfl_xor(s2, m, 64);
    }
    float mu  = s*rn;
    float var = fmaxf(s2*rn - mu*mu, 0.f);
    float y = (val-mu)*rsqrtf(var+1e-5f)*gg + be;
    y = fmaxf(y, 0.f);
    long long oidx = (long long)wid*(TT*HID) + t*HID + f;
    if(resid) y += resid[oidx];
    if(act) out[oidx] = y;
  }
}

// ---------------- fused GRU (all 6 steps, LDS-resident h) + classifier ----------------
// block: 64 nodes, 384 threads = 6 waves; wave w owns features f0=w*8 of all gates.
__global__ __launch_bounds__(384) void k_gruF(const float* __restrict__ X,  // h2 [n][t][48]
                                              const float* __restrict__ WihT, const float* __restrict__ WhhT,
                                              const float* __restrict__ bih, const float* __restrict__ bhh,
                                              const float* __restrict__ Wc1, const float* __restrict__ bc1,
                                              const float* __restrict__ Wc2, const float* __restrict__ bc2,
                                              float* __restrict__ out){
  __shared__ float hbuf[64*48];
  __shared__ float xbuf[64*48];
  int tid = threadIdx.x;
  int blk = blockIdx.x;
  int wave = tid>>6, lane = tid&63;
  int f0 = wave*8;
  int node = blk*64 + lane;
  // zero h (384*8 = 3072 floats)
#pragma unroll
  for(int i=0;i<8;i++) hbuf[tid*8+i] = 0.f;
  // staging mapping: thread -> (node 0..63, 8-float part 0..5)
  int s_node = tid/6, s_part = tid-6*s_node;
  long long g_node = (long long)blk*64 + s_node; if(g_node>=NN) g_node=NN-1;
  const float* xrow = X + g_node*(TT*HID) + s_part*8;
  float* xdst = xbuf + s_node*48 + s_part*8;
  // per-thread gate biases
  float rb[8], zb[8], nbi[8], nbh[8];
#pragma unroll
  for(int j=0;j<8;j++){
    int f=f0+j;
    rb[j]  = bih[f]    + bhh[f];
    zb[j]  = bih[48+f] + bhh[48+f];
    nbi[j] = bih[96+f];
    nbh[j] = bhh[96+f];
  }

  for(int t=0;t<TT;t++){
    // stage x_t (xbuf reads of step t-1 finished before last barrier)
    {
      const float4* s4 = reinterpret_cast<const float4*>(xrow + t*HID);
      float4 a=s4[0], b=s4[1];
      reinterpret_cast<float4*>(xdst)[0]=a;
      reinterpret_cast<float4*>(xdst)[1]=b;
    }
    __syncthreads();   // xbuf + hbuf ready
    float ra[8],za[8],ia[8],ha[8];
#pragma unroll
    for(int j=0;j<8;j++){ ra[j]=0.f; za[j]=0.f; ia[j]=0.f; ha[j]=0.f; }
    const float4* xls = reinterpret_cast<const float4*>(xbuf + lane*48);
    const float4* hls = reinterpret_cast<const float4*>(hbuf + lane*48);
#pragma unroll 3
    for(int k4=0;k4<12;k4++){
      float4 xv = xls[k4];
      float4 hv = hls[k4];
#pragma unroll
      for(int q=0;q<4;q++){
        float xk = (&xv.x)[q], hk = (&hv.x)[q];
        const float* wi = WihT + (4*k4+q)*144 + f0;
        const float* wh = WhhT + (4*k4+q)*144 + f0;
        float4 wir0=*reinterpret_cast<const float4*>(wi);
        float4 wir1=*reinterpret_cast<const float4*>(wi+4);
        float4 wiz0=*reinterpret_cast<const float4*>(wi+48);
        float4 wiz1=*reinterpret_cast<const float4*>(wi+52);
        float4 win0=*reinterpret_cast<const float4*>(wi+96);
        float4 win1=*reinterpret_cast<const float4*>(wi+100);
        float4 whr0=*reinterpret_cast<const float4*>(wh);
        float4 whr1=*reinterpret_cast<const float4*>(wh+4);
        float4 whz0=*reinterpret_cast<const float4*>(wh+48);
        float4 whz1=*reinterpret_cast<const float4*>(wh+52);
        float4 whn0=*reinterpret_cast<const float4*>(wh+96);
        float4 whn1=*reinterpret_cast<const float4*>(wh+100);
#pragma unroll
        for(int c=0;c<4;c++){
          ra[c]  = fmaf(xk,(&wir0.x)[c],ra[c]);   ra[c]  = fmaf(hk,(&whr0.x)[c],ra[c]);
          ra[4+c]= fmaf(xk,(&wir1.x)[c],ra[4+c]); ra[4+c]= fmaf(hk,(&whr1.x)[c],ra[4+c]);
          za[c]  = fmaf(xk,(&wiz0.x)[c],za[c]);   za[c]  = fmaf(hk,(&whz0.x)[c],za[c]);
          za[4+c]= fmaf(xk,(&wiz1.x)[c],za[4+c]); za[4+c]= fmaf(hk,(&whz1.x)[c],za[4+c]);
          ia[c]  = fmaf(xk,(&win0.x)[c],ia[c]);   ia[4+c]= fmaf(xk,(&win1.x)[c],ia[4+c]);
          ha[c]  = fmaf(hk,(&whn0.x)[c],ha[c]);   ha[4+c]= fmaf(hk,(&whn1.x)[c],ha[4+c]);
        }
      }
    }
    float hnew[8];
#pragma unroll
    for(int j=0;j<8;j++){
      float r  = sigmoidf_(ra[j]+rb[j]);
      float zg = sigmoidf_(za[j]+zb[j]);
      float ng = tanhf(ia[j]+nbi[j] + r*(ha[j]+nbh[j]));
      float ho = hbuf[lane*48+f0+j];
      hnew[j] = (1.f-zg)*ng + zg*ho;
    }
    __syncthreads();   // all reads of hbuf/xbuf done
#pragma unroll
    for(int j=0;j<8;j++) hbuf[lane*48+f0+j] = hnew[j];
  }
  __syncthreads();     // final h ready
  // classifier epilogue: wave 0, one node per lane
  if(wave==0 && node<NN){
    const float* hr = hbuf + lane*48;
    float hv[24];
#pragma unroll
    for(int j=0;j<24;j++) hv[j]=bc1[j];
    for(int k=0;k<HID;k++){
      float xk = hr[k];
      const float* wr = Wc1 + k*24;
#pragma unroll
      for(int j=0;j<24;j++) hv[j] = fmaf(xk, wr[j], hv[j]);
    }
    float l0=bc2[0], l1=bc2[1];
#pragma unroll
    for(int j=0;j<24;j++){
      float a = fmaxf(hv[j],0.f);
      l0 = fmaf(a, Wc2[2*j],   l0);
      l1 = fmaf(a, Wc2[2*j+1], l1);
    }
    reinterpret_cast<float2*>(out)[node] = make_float2(l0,l1);
  }
}

static inline size_t al256(size_t x){ return (x+255)&~(size_t)255; }

extern "C" void kernel_launch(void* const* d_in, const int* in_sizes, int n_in,
                              void* d_out, int out_size, void* d_ws, size_t ws_size,
                              hipStream_t stream){
  const float* x_seq=(const float*)d_in[0];
  const int*   ei   =(const int*)d_in[1];
  const float* ew   =(const float*)d_in[2];
  const float* W0=(const float*)d_in[3];  const float* b0=(const float*)d_in[4];
  const float* g0=(const float*)d_in[5];  const float* be0=(const float*)d_in[6];
  const float* W1=(const float*)d_in[7];  const float* b1=(const float*)d_in[8];
  const float* g1=(const float*)d_in[9];  const float* be1=(const float*)d_in[10];
  const float* Wih=(const float*)d_in[11];const float* Whh=(const float*)d_in[12];
  const float* bih=(const float*)d_in[13];const float* bhh=(const float*)d_in[14];
  const float* Wc1=(const float*)d_in[15];const float* bc1=(const float*)d_in[16];
  const float* Wc2=(const float*)d_in[17];const float* bc2=(const float*)d_in[18];
  float* outp=(float*)d_out;

  char* p=(char*)d_ws; size_t off=0;
  auto alloc=[&](size_t bytes)->void*{ void* r=p+off; off=al256(off+bytes); return r; };
  float* deg    =(float*)alloc((size_t)NN*4);
  float* dis    =(float*)alloc((size_t)NN*4);
  int*   cnt    =(int*)  alloc((size_t)NN*4);
  int*   offs   =(int*)  alloc((size_t)(NN+1)*4);
  int*   cursor =(int*)  alloc((size_t)NN*4);
  int*   bsum   =(int*)  alloc((size_t)NB*4);
  int*   bpre   =(int*)  alloc((size_t)NB*4);
  int2*  csr    =(int2*) alloc((size_t)NE*8);
  float* WihT   =(float*)alloc((size_t)144*48*4);
  float* WhhT   =(float*)alloc((size_t)144*48*4);
  unsigned* A   =(unsigned*)alloc((size_t)NN*576 + 1024);   // bf16 [n][f][t6], 576B/row
  float* h1     =(float*)alloc((size_t)NN*TT*HID*4);
  float* h2     =(float*)alloc((size_t)NN*TT*HID*4);

  const int GN=(NN+255)/256, GE=(NE+255)/256;
  const int GMM=(NN*4+255)/256;          // 4 threads/node
  const int GAGG=(NN*64+255)/256;        // 1 wave/node
  const int GGRU=(NN+63)/64;             // 64 nodes/block

  k_setup  <<<GN,256,0,stream>>>(deg,cnt,Wih,Whh,WihT,WhhT);
  k_degcnt <<<GE,256,0,stream>>>(ei,ew,deg,cnt);
  k_partA  <<<NB,256,0,stream>>>(cnt,deg,dis,bsum);
  k_midB   <<<1,256,0,stream>>>(bsum,bpre,offs);
  k_offsC  <<<NB,256,0,stream>>>(cnt,bpre,offs,cursor);
  k_scatter<<<GE,256,0,stream>>>(ei,ew,dis,cursor,csr);

  // layer 0
  k_mm0<<<GMM,256,0,stream>>>(x_seq, W0, A);
  k_agg<<<GAGG,256,0,stream>>>(A,b0,g0,be0,nullptr,h1,offs,csr,dis);
  // layer 1 (residual = h1)
  k_mm1<<<GMM,256,0,stream>>>(h1, W1, A);
  k_agg<<<GAGG,256,0,stream>>>(A,b1,g1,be1,h1,h2,offs,csr,dis);
  // fused GRU (6 steps) + classifier
  k_gruF<<<GGRU,384,0,stream>>>(h2, WihT,WhhT,bih,bhh, Wc1,bc1,Wc2,bc2, outp);
}

// Round 5
// 782.088 us; speedup vs baseline: 1.5784x; 1.5784x over previous
//
#include <hip/hip_runtime.h>
#include <math.h>

#define NN 50000
#define NE 800000
#define TT 6
#define HID 48
#define NB 196   // (NN+255)/256
#define LROW 129 // LDS row stride (mod 32 == 1 -> conflict-free)

__device__ __forceinline__ float sigmoidf_(float x){ return 1.0f/(1.0f+__expf(-x)); }
__device__ __forceinline__ float tanhf_(float x){
  float xc = fminf(fmaxf(x,-15.f),15.f);
  float t = __expf(2.f*xc);
  return (t-1.f)/(t+1.f);
}
__device__ __forceinline__ unsigned f2bf(float x){
  unsigned u = __float_as_uint(x);
  return (u + 0x7fffu + ((u>>16)&1u)) >> 16;   // RNE to bf16
}
__device__ __forceinline__ unsigned pack2(float a, float b){
  return f2bf(a) | (f2bf(b)<<16);
}
__device__ __forceinline__ float bflo(unsigned u){ return __uint_as_float(u<<16); }
__device__ __forceinline__ float bfhi(unsigned u){ return __uint_as_float(u & 0xffff0000u); }

struct U3 { unsigned x,y,z; };

// 256-thread inclusive block scan (4 waves of 64)
__device__ __forceinline__ int block_scan_incl(int x, int* wsum){
  int lane = threadIdx.x & 63, w = threadIdx.x >> 6;
  int v = x;
#pragma unroll
  for(int d=1; d<64; d<<=1){
    int u = __shfl_up(v, d, 64);
    if(lane >= d) v += u;
  }
  if(lane==63) wsum[w] = v;
  __syncthreads();
  int add = 0;
#pragma unroll
  for(int k=0;k<3;k++) if(w>k) add += wsum[k];
  return v + add;
}

// ---------------- setup: deg/cnt init + GRU weight repack ----------------
// Wg layout: [wave 0..5][k 0..47][48]: per (w,k): wir(8) wiz(8) win(8) whr(8) whz(8) whn(8)
// column = w*8+j;  gi[f] = sum_k x[k]*Wih[f*48+k]
__global__ __launch_bounds__(256) void k_setup(float* deg, int* cnt,
                                               const float* __restrict__ Wih, const float* __restrict__ Whh,
                                               float* Wg){
  int i = blockIdx.x*256+threadIdx.x;
  if(i<NN){ deg[i]=1.0f; cnt[i]=0; }          // self-loop weight 1 pre-added
  if(i < 6*48*48){
    int w = i/2304, rem = i%2304;
    int k = rem/48, g8 = rem%48;
    int g = g8>>3, j = g8&7;
    int col = w*8+j;
    float v = (g<3) ? Wih[(g*48+col)*48 + k] : Whh[((g-3)*48+col)*48 + k];
    Wg[i] = v;
  }
}

__global__ __launch_bounds__(256) void k_degcnt(const int* __restrict__ ei, const float* __restrict__ ew,
                                                float* deg, int* cnt){
  int e = blockIdx.x*256+threadIdx.x;
  if(e<NE){
    int c = ei[NE+e];
    atomicAdd(&deg[c], ew[e]);
    atomicAdd(&cnt[c], 1);
  }
}

// phase A: per-block sums of cnt, plus dis = rsqrt(deg)
__global__ __launch_bounds__(256) void k_partA(const int* __restrict__ cnt, const float* __restrict__ deg,
                                               float* dis, int* bsum){
  __shared__ int wsum[4];
  int i = blockIdx.x*256+threadIdx.x;
  int x = 0;
  if(i<NN){
    x = cnt[i];
    float d = deg[i];
    dis[i] = d>0.f ? rsqrtf(fmaxf(d,1e-12f)) : 0.f;
  }
  int lane = threadIdx.x & 63, w = threadIdx.x >> 6;
  int v = x;
#pragma unroll
  for(int m=32;m>=1;m>>=1) v += __shfl_xor(v, m, 64);
  if(lane==0) wsum[w]=v;
  __syncthreads();
  if(threadIdx.x==0) bsum[blockIdx.x] = wsum[0]+wsum[1]+wsum[2]+wsum[3];
}

// phase B: exclusive scan of 196 block sums
__global__ __launch_bounds__(256) void k_midB(const int* __restrict__ bsum, int* bpre, int* offs){
  __shared__ int wsum[4];
  int t = threadIdx.x;
  int x = (t<NB)? bsum[t] : 0;
  int incl = block_scan_incl(x, wsum);
  if(t<NB) bpre[t] = incl - x;
  if(t==255) offs[NN] = incl;   // total
}

// phase C: per-block exclusive scan of cnt + bpre -> offs/cursor
__global__ __launch_bounds__(256) void k_offsC(const int* __restrict__ cnt, const int* __restrict__ bpre,
                                               int* offs, int* cursor){
  __shared__ int wsum[4];
  int i = blockIdx.x*256+threadIdx.x;
  int x = (i<NN)? cnt[i] : 0;
  int incl = block_scan_incl(x, wsum);
  int val = bpre[blockIdx.x] + incl - x;
  if(i<NN){ offs[i]=val; cursor[i]=val; }
}

__global__ __launch_bounds__(256) void k_scatter(const int* __restrict__ ei, const float* __restrict__ ew,
                                                 const float* __restrict__ dis, int* cursor,
                                                 int2* __restrict__ csr){
  int e = blockIdx.x*256+threadIdx.x;
  if(e<NE){
    int r=ei[e], c=ei[NE+e];
    int pos=atomicAdd(&cursor[c],1);
    int2 v; v.x=r; v.y=__float_as_int(dis[r]*ew[e]*dis[c]);
    csr[pos]=v;
  }
}

// ---------------- layer-0 matmul: wave = feature slice (uniform), lane = node ----------------
// A row per node = 144 words (576B): feature f at word offset f*3, bf16 [t6].
__global__ __launch_bounds__(256) void k_mm0(const float* __restrict__ X, const float* __restrict__ W,
                                             unsigned* __restrict__ A){
  int s = __builtin_amdgcn_readfirstlane(threadIdx.x>>6);   // 0..3, wave-uniform
  int n = blockIdx.x*64 + (threadIdx.x&63);
  if(n>=NN) return;
  const float* xb = X + (long long)n*64;
  const float* wb = W + 12*s;
  float acc[TT][12];
#pragma unroll
  for(int t=0;t<TT;t++)
#pragma unroll
    for(int j=0;j<12;j++) acc[t][j]=0.f;
#pragma unroll 2
  for(int k4=0;k4<16;k4++){
    float4 xv[TT];
#pragma unroll
    for(int t=0;t<TT;t++) xv[t] = *reinterpret_cast<const float4*>(xb + (long long)t*NN*64 + 4*k4);
#pragma unroll
    for(int q=0;q<4;q++){
      const float* wr = wb + (4*k4+q)*HID;
      float w[12];
#pragma unroll
      for(int j=0;j<12;j++) w[j]=wr[j];   // uniform addr -> s_load
#pragma unroll
      for(int t=0;t<TT;t++){
        float xs = (&xv[t].x)[q];
#pragma unroll
        for(int j=0;j<12;j++) acc[t][j] = fmaf(xs, w[j], acc[t][j]);
      }
    }
  }
  unsigned buf[36];
#pragma unroll
  for(int j=0;j<12;j++){
    buf[3*j  ]=pack2(acc[0][j],acc[1][j]);
    buf[3*j+1]=pack2(acc[2][j],acc[3][j]);
    buf[3*j+2]=pack2(acc[4][j],acc[5][j]);
  }
  uint4* o4 = reinterpret_cast<uint4*>(A + (long long)n*144 + 36*s);
#pragma unroll
  for(int q=0;q<9;q++) o4[q] = make_uint4(buf[4*q],buf[4*q+1],buf[4*q+2],buf[4*q+3]);
}

// ---------------- layer-1 matmul (K=48), input fp32 [n][t][48] ----------------
__global__ __launch_bounds__(256) void k_mm1(const float* __restrict__ X, const float* __restrict__ W,
                                             unsigned* __restrict__ A){
  int s = __builtin_amdgcn_readfirstlane(threadIdx.x>>6);
  int n = blockIdx.x*64 + (threadIdx.x&63);
  if(n>=NN) return;
  const float* xb = X + (long long)n*(TT*HID);
  const float* wb = W + 12*s;
  float acc[TT][12];
#pragma unroll
  for(int t=0;t<TT;t++)
#pragma unroll
    for(int j=0;j<12;j++) acc[t][j]=0.f;
#pragma unroll 2
  for(int k4=0;k4<12;k4++){
    float4 xv[TT];
#pragma unroll
    for(int t=0;t<TT;t++) xv[t] = *reinterpret_cast<const float4*>(xb + t*HID + 4*k4);
#pragma unroll
    for(int q=0;q<4;q++){
      const float* wr = wb + (4*k4+q)*HID;
      float w[12];
#pragma unroll
      for(int j=0;j<12;j++) w[j]=wr[j];
#pragma unroll
      for(int t=0;t<TT;t++){
        float xs = (&xv[t].x)[q];
#pragma unroll
        for(int j=0;j<12;j++) acc[t][j] = fmaf(xs, w[j], acc[t][j]);
      }
    }
  }
  unsigned buf[36];
#pragma unroll
  for(int j=0;j<12;j++){
    buf[3*j  ]=pack2(acc[0][j],acc[1][j]);
    buf[3*j+1]=pack2(acc[2][j],acc[3][j]);
    buf[3*j+2]=pack2(acc[4][j],acc[5][j]);
  }
  uint4* o4 = reinterpret_cast<uint4*>(A + (long long)n*144 + 36*s);
#pragma unroll
  for(int q=0;q<9;q++) o4[q] = make_uint4(buf[4*q],buf[4*q+1],buf[4*q+2],buf[4*q+3]);
}

// ---------------- CSR aggregation (bf16 gather, 12B/edge-feature) + bias + LN + ReLU (+resid)
__global__ __launch_bounds__(256) void k_agg(const unsigned* __restrict__ A, const float* __restrict__ bias,
                                             const float* __restrict__ gain, const float* __restrict__ beta,
                                             const float* __restrict__ resid, float* __restrict__ out,
                                             const int* __restrict__ offs, const int2* __restrict__ csr,
                                             const float* __restrict__ dis){
  int wid = (blockIdx.x*256+threadIdx.x)>>6;
  int lane = threadIdx.x & 63;
  if(wid>=NN) return;
  const bool act = lane<HID;
  const int f = act? lane : (HID-1);
  float dn = dis[wid];
  float sw = dn*dn;
  float acc[TT];
  {
    U3 v = *reinterpret_cast<const U3*>(A + (long long)wid*144 + 3*f);
    acc[0]=sw*bflo(v.x); acc[1]=sw*bfhi(v.x);
    acc[2]=sw*bflo(v.y); acc[3]=sw*bfhi(v.y);
    acc[4]=sw*bflo(v.z); acc[5]=sw*bfhi(v.z);
  }
  int e0=offs[wid], e1=offs[wid+1];
  int e=e0;
  for(; e+3<e1; e+=4){
    int2 i0=csr[e], i1=csr[e+1], i2=csr[e+2], i3=csr[e+3];
    U3 d0 = *reinterpret_cast<const U3*>(A + (long long)i0.x*144 + 3*f);
    U3 d1 = *reinterpret_cast<const U3*>(A + (long long)i1.x*144 + 3*f);
    U3 d2 = *reinterpret_cast<const U3*>(A + (long long)i2.x*144 + 3*f);
    U3 d3 = *reinterpret_cast<const U3*>(A + (long long)i3.x*144 + 3*f);
    float n0=__int_as_float(i0.y), n1=__int_as_float(i1.y);
    float n2=__int_as_float(i2.y), n3=__int_as_float(i3.y);
    acc[0]=fmaf(n0,bflo(d0.x),acc[0]); acc[1]=fmaf(n0,bfhi(d0.x),acc[1]);
    acc[2]=fmaf(n0,bflo(d0.y),acc[2]); acc[3]=fmaf(n0,bfhi(d0.y),acc[3]);
    acc[4]=fmaf(n0,bflo(d0.z),acc[4]); acc[5]=fmaf(n0,bfhi(d0.z),acc[5]);
    acc[0]=fmaf(n1,bflo(d1.x),acc[0]); acc[1]=fmaf(n1,bfhi(d1.x),acc[1]);
    acc[2]=fmaf(n1,bflo(d1.y),acc[2]); acc[3]=fmaf(n1,bfhi(d1.y),acc[3]);
    acc[4]=fmaf(n1,bflo(d1.z),acc[4]); acc[5]=fmaf(n1,bfhi(d1.z),acc[5]);
    acc[0]=fmaf(n2,bflo(d2.x),acc[0]); acc[1]=fmaf(n2,bfhi(d2.x),acc[1]);
    acc[2]=fmaf(n2,bflo(d2.y),acc[2]); acc[3]=fmaf(n2,bfhi(d2.y),acc[3]);
    acc[4]=fmaf(n2,bflo(d2.z),acc[4]); acc[5]=fmaf(n2,bfhi(d2.z),acc[5]);
    acc[0]=fmaf(n3,bflo(d3.x),acc[0]); acc[1]=fmaf(n3,bfhi(d3.x),acc[1]);
    acc[2]=fmaf(n3,bflo(d3.y),acc[2]); acc[3]=fmaf(n3,bfhi(d3.y),acc[3]);
    acc[4]=fmaf(n3,bflo(d3.z),acc[4]); acc[5]=fmaf(n3,bfhi(d3.z),acc[5]);
  }
  for(; e<e1; ++e){
    int2 i0=csr[e];
    U3 d0 = *reinterpret_cast<const U3*>(A + (long long)i0.x*144 + 3*f);
    float n0=__int_as_float(i0.y);
    acc[0]=fmaf(n0,bflo(d0.x),acc[0]); acc[1]=fmaf(n0,bfhi(d0.x),acc[1]);
    acc[2]=fmaf(n0,bflo(d0.y),acc[2]); acc[3]=fmaf(n0,bfhi(d0.y),acc[3]);
    acc[4]=fmaf(n0,bflo(d0.z),acc[4]); acc[5]=fmaf(n0,bfhi(d0.z),acc[5]);
  }
  float bb = bias[f], gg = gain[f], be = beta[f];
  const float rn = 1.0f/HID;
#pragma unroll
  for(int t=0;t<TT;t++){
    float val = acc[t] + bb;
    float v = act? val : 0.f;
    float s = v, s2 = v*v;
#pragma unroll
    for(int m=32;m>=1;m>>=1){
      s  += __shfl_xor(s,  m, 64);
      s2 += __shfl_xor(s2, m, 64);
    }
    float mu  = s*rn;
    float var = fmaxf(s2*rn - mu*mu, 0.f);
    float y = (val-mu)*rsqrtf(var+1e-5f)*gg + be;
    y = fmaxf(y, 0.f);
    long long oidx = (long long)wid*(TT*HID) + t*HID + f;
    if(resid) y += resid[oidx];
    if(act) out[oidx] = y;
  }
}

// ---------------- fused GRU (6 steps) + classifier ----------------
// block: 128 nodes, 384 threads = 6 waves. Wave wv owns 8 features (f0=wv*8) of all gates,
// each lane handles 2 nodes (lane, 64+lane). h/x transposed in LDS [48][129] (conflict-free).
// Weights repacked in Wg so per-(wv,k) block is 48 contiguous floats at a wave-uniform address.
__global__ __launch_bounds__(384) void k_gruF(const float* __restrict__ X,  // h2 [n][t][48]
                                              const float* __restrict__ Wg,
                                              const float* __restrict__ bih, const float* __restrict__ bhh,
                                              const float* __restrict__ Wc1, const float* __restrict__ bc1,
                                              const float* __restrict__ Wc2, const float* __restrict__ bc2,
                                              float* __restrict__ out){
  __shared__ float xbuf[48*LROW];
  __shared__ float hbuf[48*LROW];
  int tid = threadIdx.x;
  int wv = __builtin_amdgcn_readfirstlane(tid>>6);   // 0..5, uniform
  int lane = tid & 63;
  int f0 = wv*8;
  long long nbase = (long long)blockIdx.x*128;
  int n0 = lane, n1 = 64+lane;

  for(int i=tid;i<48*LROW;i+=384) hbuf[i]=0.f;

  // per-thread gate biases (uniform addresses)
  float rb[8], zb[8], nbi[8], nbh[8];
#pragma unroll
  for(int j=0;j<8;j++){
    int f=f0+j;
    rb[j]  = bih[f]    + bhh[f];
    zb[j]  = bih[48+f] + bhh[48+f];
    nbi[j] = bih[96+f];
    nbh[j] = bhh[96+f];
  }

  for(int t=0;t<TT;t++){
    // stage x_t transposed: 1536 float4-chunks (128 nodes x 12), 4 per thread
#pragma unroll
    for(int i=0;i<4;i++){
      int c = tid + 384*i;
      int nd = c/12, fc = c - nd*12;
      long long gn = nbase + nd; if(gn>NN-1) gn=NN-1;
      float4 xv = *reinterpret_cast<const float4*>(X + gn*(TT*HID) + t*HID + fc*4);
      int base = (fc*4)*LROW + nd;
      xbuf[base]        = xv.x;
      xbuf[base+LROW]   = xv.y;
      xbuf[base+2*LROW] = xv.z;
      xbuf[base+3*LROW] = xv.w;
    }
    __syncthreads();   // xbuf + hbuf ready

    float ra0[8],za0[8],ia0[8],ha0[8],ra1[8],za1[8],ia1[8],ha1[8];
#pragma unroll
    for(int j=0;j<8;j++){ ra0[j]=za0[j]=ia0[j]=ha0[j]=0.f; ra1[j]=za1[j]=ia1[j]=ha1[j]=0.f; }

#pragma unroll 2
    for(int k=0;k<48;k++){
      const float* wp = Wg + ((wv*48 + k)*48);   // uniform -> s_load
      float ws[48];
#pragma unroll
      for(int q=0;q<48;q++) ws[q]=wp[q];
      float xk0 = xbuf[k*LROW+n0], xk1 = xbuf[k*LROW+n1];
      float hk0 = hbuf[k*LROW+n0], hk1 = hbuf[k*LROW+n1];
#pragma unroll
      for(int j=0;j<8;j++){
        float wir=ws[j], wiz=ws[8+j], win=ws[16+j], whr=ws[24+j], whz=ws[32+j], whn=ws[40+j];
        ra0[j]=fmaf(xk0,wir,ra0[j]); ra0[j]=fmaf(hk0,whr,ra0[j]);
        za0[j]=fmaf(xk0,wiz,za0[j]); za0[j]=fmaf(hk0,whz,za0[j]);
        ia0[j]=fmaf(xk0,win,ia0[j]); ha0[j]=fmaf(hk0,whn,ha0[j]);
        ra1[j]=fmaf(xk1,wir,ra1[j]); ra1[j]=fmaf(hk1,whr,ra1[j]);
        za1[j]=fmaf(xk1,wiz,za1[j]); za1[j]=fmaf(hk1,whz,za1[j]);
        ia1[j]=fmaf(xk1,win,ia1[j]); ha1[j]=fmaf(hk1,whn,ha1[j]);
      }
    }

    float hn0[8], hn1[8];
#pragma unroll
    for(int j=0;j<8;j++){
      int fw = (f0+j)*LROW;
      float r0  = sigmoidf_(ra0[j]+rb[j]);
      float z0  = sigmoidf_(za0[j]+zb[j]);
      float ng0 = tanhf_(ia0[j]+nbi[j] + r0*(ha0[j]+nbh[j]));
      hn0[j] = (1.f-z0)*ng0 + z0*hbuf[fw+n0];
      float r1  = sigmoidf_(ra1[j]+rb[j]);
      float z1  = sigmoidf_(za1[j]+zb[j]);
      float ng1 = tanhf_(ia1[j]+nbi[j] + r1*(ha1[j]+nbh[j]));
      hn1[j] = (1.f-z1)*ng1 + z1*hbuf[fw+n1];
    }
    __syncthreads();   // all reads done before overwrite
#pragma unroll
    for(int j=0;j<8;j++){
      int fw = (f0+j)*LROW;
      hbuf[fw+n0] = hn0[j];
      hbuf[fw+n1] = hn1[j];
    }
  }
  __syncthreads();     // final h ready

  // classifier epilogue: waves 0-1 cover the block's 128 nodes
  if(wv<2){
    int nd = wv*64 + lane;
    long long gn = nbase + nd;
    if(gn<NN){
      float hv[24];
#pragma unroll
      for(int j=0;j<24;j++) hv[j]=bc1[j];
      for(int k=0;k<HID;k++){
        float xk = hbuf[k*LROW+nd];
        const float* wr = Wc1 + k*24;   // uniform -> s_load
#pragma unroll
        for(int j=0;j<24;j++) hv[j] = fmaf(xk, wr[j], hv[j]);
      }
      float l0=bc2[0], l1=bc2[1];
#pragma unroll
      for(int j=0;j<24;j++){
        float a = fmaxf(hv[j],0.f);
        l0 = fmaf(a, Wc2[2*j],   l0);
        l1 = fmaf(a, Wc2[2*j+1], l1);
      }
      reinterpret_cast<float2*>(out)[gn] = make_float2(l0,l1);
    }
  }
}

static inline size_t al256(size_t x){ return (x+255)&~(size_t)255; }

extern "C" void kernel_launch(void* const* d_in, const int* in_sizes, int n_in,
                              void* d_out, int out_size, void* d_ws, size_t ws_size,
                              hipStream_t stream){
  const float* x_seq=(const float*)d_in[0];
  const int*   ei   =(const int*)d_in[1];
  const float* ew   =(const float*)d_in[2];
  const float* W0=(const float*)d_in[3];  const float* b0=(const float*)d_in[4];
  const float* g0=(const float*)d_in[5];  const float* be0=(const float*)d_in[6];
  const float* W1=(const float*)d_in[7];  const float* b1=(const float*)d_in[8];
  const float* g1=(const float*)d_in[9];  const float* be1=(const float*)d_in[10];
  const float* Wih=(const float*)d_in[11];const float* Whh=(const float*)d_in[12];
  const float* bih=(const float*)d_in[13];const float* bhh=(const float*)d_in[14];
  const float* Wc1=(const float*)d_in[15];const float* bc1=(const float*)d_in[16];
  const float* Wc2=(const float*)d_in[17];const float* bc2=(const float*)d_in[18];
  float* outp=(float*)d_out;

  char* p=(char*)d_ws; size_t off=0;
  auto alloc=[&](size_t bytes)->void*{ void* r=p+off; off=al256(off+bytes); return r; };
  float* deg    =(float*)alloc((size_t)NN*4);
  float* dis    =(float*)alloc((size_t)NN*4);
  int*   cnt    =(int*)  alloc((size_t)NN*4);
  int*   offs   =(int*)  alloc((size_t)(NN+1)*4);
  int*   cursor =(int*)  alloc((size_t)NN*4);
  int*   bsum   =(int*)  alloc((size_t)NB*4);
  int*   bpre   =(int*)  alloc((size_t)NB*4);
  int2*  csr    =(int2*) alloc((size_t)NE*8);
  float* Wg     =(float*)alloc((size_t)6*48*48*4);
  unsigned* A   =(unsigned*)alloc((size_t)NN*576 + 1024);   // bf16 [n][f][t6], 576B/row
  float* h1     =(float*)alloc((size_t)NN*TT*HID*4);
  float* h2     =(float*)alloc((size_t)NN*TT*HID*4);

  const int GN=(NN+255)/256, GE=(NE+255)/256;
  const int GMM=(NN+63)/64;              // 64 nodes/block, 4 waves (feature slices)
  const int GAGG=(NN*64+255)/256;        // 1 wave/node
  const int GGRU=(NN+127)/128;           // 128 nodes/block

  k_setup  <<<GN,256,0,stream>>>(deg,cnt,Wih,Whh,Wg);
  k_degcnt <<<GE,256,0,stream>>>(ei,ew,deg,cnt);
  k_partA  <<<NB,256,0,stream>>>(cnt,deg,dis,bsum);
  k_midB   <<<1,256,0,stream>>>(bsum,bpre,offs);
  k_offsC  <<<NB,256,0,stream>>>(cnt,bpre,offs,cursor);
  k_scatter<<<GE,256,0,stream>>>(ei,ew,dis,cursor,csr);

  // layer 0
  k_mm0<<<GMM,256,0,stream>>>(x_seq, W0, A);
  k_agg<<<GAGG,256,0,stream>>>(A,b0,g0,be0,nullptr,h1,offs,csr,dis);
  // layer 1 (residual = h1)
  k_mm1<<<GMM,256,0,stream>>>(h1, W1, A);
  k_agg<<<GAGG,256,0,stream>>>(A,b1,g1,be1,h1,h2,offs,csr,dis);
  // fused GRU (6 steps) + classifier
  k_gruF<<<GGRU,384,0,stream>>>(h2, Wg, bih,bhh, Wc1,bc1,Wc2,bc2, outp);
}

// Round 6
// 705.570 us; speedup vs baseline: 1.7496x; 1.1084x over previous
//
#include <hip/hip_runtime.h>
#include <math.h>

#define NN 50000
#define NE 800000
#define TT 6
#define HID 48
#define NB 196   // (NN+255)/256
#define LR 65    // LDS row stride for 64 nodes (mod 32 == 1 -> conflict-free)

__device__ __forceinline__ float sigmoidf_(float x){ return 1.0f/(1.0f+__expf(-x)); }
__device__ __forceinline__ float tanhf_(float x){
  float xc = fminf(fmaxf(x,-15.f),15.f);
  float t = __expf(2.f*xc);
  return (t-1.f)/(t+1.f);
}
__device__ __forceinline__ unsigned f2bf(float x){
  unsigned u = __float_as_uint(x);
  return (u + 0x7fffu + ((u>>16)&1u)) >> 16;   // RNE to bf16
}
__device__ __forceinline__ unsigned pack2(float a, float b){
  return f2bf(a) | (f2bf(b)<<16);
}
__device__ __forceinline__ float bflo(unsigned u){ return __uint_as_float(u<<16); }
__device__ __forceinline__ float bfhi(unsigned u){ return __uint_as_float(u & 0xffff0000u); }

struct U3 { unsigned x,y,z; };

// 256-thread inclusive block scan (4 waves of 64)
__device__ __forceinline__ int block_scan_incl(int x, int* wsum){
  int lane = threadIdx.x & 63, w = threadIdx.x >> 6;
  int v = x;
#pragma unroll
  for(int d=1; d<64; d<<=1){
    int u = __shfl_up(v, d, 64);
    if(lane >= d) v += u;
  }
  if(lane==63) wsum[w] = v;
  __syncthreads();
  int add = 0;
#pragma unroll
  for(int k=0;k<3;k++) if(w>k) add += wsum[k];
  return v + add;
}

// ---------------- setup: cnt init + GRU weight repack ----------------
// Wg layout: [wave 0..5][k 0..47][48]: per (w,k): wir(8) wiz(8) win(8) whr(8) whz(8) whn(8)
__global__ __launch_bounds__(256) void k_setup(int* cnt,
                                               const float* __restrict__ Wih, const float* __restrict__ Whh,
                                               float* Wg){
  int i = blockIdx.x*256+threadIdx.x;
  if(i<NN) cnt[i]=0;
  if(i < 6*48*48){
    int w = i/2304, rem = i%2304;
    int k = rem/48, g8 = rem%48;
    int g = g8>>3, j = g8&7;
    int col = w*8+j;
    float v = (g<3) ? Wih[(g*48+col)*48 + k] : Whh[((g-3)*48+col)*48 + k];
    Wg[i] = v;
  }
}

// single atomic per edge: rank within destination bucket
__global__ __launch_bounds__(256) void k_cnt(const int* __restrict__ ei, int* cnt, int* pos){
  int e = blockIdx.x*256+threadIdx.x;
  if(e<NE){
    int c = ei[NE+e];
    pos[e] = atomicAdd(&cnt[c], 1);
  }
}

// phase A: per-block sums of cnt
__global__ __launch_bounds__(256) void k_partA(const int* __restrict__ cnt, int* bsum){
  __shared__ int wsum[4];
  int i = blockIdx.x*256+threadIdx.x;
  int x = (i<NN)? cnt[i] : 0;
  int lane = threadIdx.x & 63, w = threadIdx.x >> 6;
  int v = x;
#pragma unroll
  for(int m=32;m>=1;m>>=1) v += __shfl_xor(v, m, 64);
  if(lane==0) wsum[w]=v;
  __syncthreads();
  if(threadIdx.x==0) bsum[blockIdx.x] = wsum[0]+wsum[1]+wsum[2]+wsum[3];
}

// phase B: exclusive scan of 196 block sums
__global__ __launch_bounds__(256) void k_midB(const int* __restrict__ bsum, int* bpre, int* offs){
  __shared__ int wsum[4];
  int t = threadIdx.x;
  int x = (t<NB)? bsum[t] : 0;
  int incl = block_scan_incl(x, wsum);
  if(t<NB) bpre[t] = incl - x;
  if(t==255) offs[NN] = incl;   // total
}

// phase C: per-block exclusive scan of cnt + bpre -> offs
__global__ __launch_bounds__(256) void k_offsC(const int* __restrict__ cnt, const int* __restrict__ bpre,
                                               int* offs){
  __shared__ int wsum[4];
  int i = blockIdx.x*256+threadIdx.x;
  int x = (i<NN)? cnt[i] : 0;
  int incl = block_scan_incl(x, wsum);
  if(i<NN) offs[i] = bpre[blockIdx.x] + incl - x;
}

// atomic-free scatter: csr[offs[c]+pos[e]] = (row, ew)
__global__ __launch_bounds__(256) void k_scatter(const int* __restrict__ ei, const float* __restrict__ ew,
                                                 const int* __restrict__ offs, const int* __restrict__ pos,
                                                 int2* __restrict__ csr){
  int e = blockIdx.x*256+threadIdx.x;
  if(e<NE){
    int c = ei[NE+e];
    int2 v; v.x = ei[e]; v.y = __float_as_int(ew[e]);
    csr[offs[c]+pos[e]] = v;
  }
}

// deg = 1 + row-sum of ew (atomic-free), dis = rsqrt(deg)  [deg>=1 always]
__global__ __launch_bounds__(256) void k_deg(const int2* __restrict__ csr, const int* __restrict__ offs,
                                             float* dis){
  int i = blockIdx.x*256+threadIdx.x;
  if(i<NN){
    float s = 1.f;
    int e0=offs[i], e1=offs[i+1];
    for(int j=e0;j<e1;j++) s += __int_as_float(csr[j].y);
    dis[i] = rsqrtf(s);
  }
}

// patch edge norm in place: y = dis[r]*ew   (dis[c] factored out in k_agg)
__global__ __launch_bounds__(256) void k_normE(int2* __restrict__ csr, const float* __restrict__ dis){
  int j = blockIdx.x*256+threadIdx.x;
  if(j<NE){
    int2 v = csr[j];
    v.y = __float_as_int(dis[v.x]*__int_as_float(v.y));
    csr[j] = v;
  }
}

// ---------------- layer-0 matmul: wave = feature slice (uniform), lane = node ----------------
// A row per node = 144 words (576B): feature f at word offset f*3, bf16 [t6].
__global__ __launch_bounds__(256) void k_mm0(const float* __restrict__ X, const float* __restrict__ W,
                                             unsigned* __restrict__ A){
  int s = __builtin_amdgcn_readfirstlane(threadIdx.x>>6);   // 0..3, wave-uniform
  int n = blockIdx.x*64 + (threadIdx.x&63);
  if(n>=NN) return;
  const float* xb = X + (long long)n*64;
  const float* wb = W + 12*s;
  float acc[TT][12];
#pragma unroll
  for(int t=0;t<TT;t++)
#pragma unroll
    for(int j=0;j<12;j++) acc[t][j]=0.f;
#pragma unroll 2
  for(int k4=0;k4<16;k4++){
    float4 xv[TT];
#pragma unroll
    for(int t=0;t<TT;t++) xv[t] = *reinterpret_cast<const float4*>(xb + (long long)t*NN*64 + 4*k4);
#pragma unroll
    for(int q=0;q<4;q++){
      const float* wr = wb + (4*k4+q)*HID;
      float w[12];
#pragma unroll
      for(int j=0;j<12;j++) w[j]=wr[j];   // uniform addr -> s_load
#pragma unroll
      for(int t=0;t<TT;t++){
        float xs = (&xv[t].x)[q];
#pragma unroll
        for(int j=0;j<12;j++) acc[t][j] = fmaf(xs, w[j], acc[t][j]);
      }
    }
  }
  unsigned buf[36];
#pragma unroll
  for(int j=0;j<12;j++){
    buf[3*j  ]=pack2(acc[0][j],acc[1][j]);
    buf[3*j+1]=pack2(acc[2][j],acc[3][j]);
    buf[3*j+2]=pack2(acc[4][j],acc[5][j]);
  }
  uint4* o4 = reinterpret_cast<uint4*>(A + (long long)n*144 + 36*s);
#pragma unroll
  for(int q=0;q<9;q++) o4[q] = make_uint4(buf[4*q],buf[4*q+1],buf[4*q+2],buf[4*q+3]);
}

// ---------------- layer-1 matmul (K=48), input fp32 [n][t][48] ----------------
__global__ __launch_bounds__(256) void k_mm1(const float* __restrict__ X, const float* __restrict__ W,
                                             unsigned* __restrict__ A){
  int s = __builtin_amdgcn_readfirstlane(threadIdx.x>>6);
  int n = blockIdx.x*64 + (threadIdx.x&63);
  if(n>=NN) return;
  const float* xb = X + (long long)n*(TT*HID);
  const float* wb = W + 12*s;
  float acc[TT][12];
#pragma unroll
  for(int t=0;t<TT;t++)
#pragma unroll
    for(int j=0;j<12;j++) acc[t][j]=0.f;
#pragma unroll 2
  for(int k4=0;k4<12;k4++){
    float4 xv[TT];
#pragma unroll
    for(int t=0;t<TT;t++) xv[t] = *reinterpret_cast<const float4*>(xb + t*HID + 4*k4);
#pragma unroll
    for(int q=0;q<4;q++){
      const float* wr = wb + (4*k4+q)*HID;
      float w[12];
#pragma unroll
      for(int j=0;j<12;j++) w[j]=wr[j];
#pragma unroll
      for(int t=0;t<TT;t++){
        float xs = (&xv[t].x)[q];
#pragma unroll
        for(int j=0;j<12;j++) acc[t][j] = fmaf(xs, w[j], acc[t][j]);
      }
    }
  }
  unsigned buf[36];
#pragma unroll
  for(int j=0;j<12;j++){
    buf[3*j  ]=pack2(acc[0][j],acc[1][j]);
    buf[3*j+1]=pack2(acc[2][j],acc[3][j]);
    buf[3*j+2]=pack2(acc[4][j],acc[5][j]);
  }
  uint4* o4 = reinterpret_cast<uint4*>(A + (long long)n*144 + 36*s);
#pragma unroll
  for(int q=0;q<9;q++) o4[q] = make_uint4(buf[4*q],buf[4*q+1],buf[4*q+2],buf[4*q+3]);
}

// ---------------- CSR aggregation (bf16 gather) + bias + LN + ReLU (+resid)
// edge norm stored = dis[r]*ew ; dis[c] factored: out = dn*(Σ nr*x_r + dn*x_c)
__global__ __launch_bounds__(256) void k_agg(const unsigned* __restrict__ A, const float* __restrict__ bias,
                                             const float* __restrict__ gain, const float* __restrict__ beta,
                                             const float* __restrict__ resid, float* __restrict__ out,
                                             const int* __restrict__ offs, const int2* __restrict__ csr,
                                             const float* __restrict__ dis){
  int wid = (blockIdx.x*256+threadIdx.x)>>6;
  int lane = threadIdx.x & 63;
  if(wid>=NN) return;
  const bool act = lane<HID;
  const int f = act? lane : (HID-1);
  float dn = dis[wid];
  float acc[TT];
  {
    U3 v = *reinterpret_cast<const U3*>(A + (long long)wid*144 + 3*f);
    acc[0]=dn*bflo(v.x); acc[1]=dn*bfhi(v.x);
    acc[2]=dn*bflo(v.y); acc[3]=dn*bfhi(v.y);
    acc[4]=dn*bflo(v.z); acc[5]=dn*bfhi(v.z);
  }
  int e0=offs[wid], e1=offs[wid+1];
  int e=e0;
  for(; e+3<e1; e+=4){
    int2 i0=csr[e], i1=csr[e+1], i2=csr[e+2], i3=csr[e+3];
    U3 d0 = *reinterpret_cast<const U3*>(A + (long long)i0.x*144 + 3*f);
    U3 d1 = *reinterpret_cast<const U3*>(A + (long long)i1.x*144 + 3*f);
    U3 d2 = *reinterpret_cast<const U3*>(A + (long long)i2.x*144 + 3*f);
    U3 d3 = *reinterpret_cast<const U3*>(A + (long long)i3.x*144 + 3*f);
    float n0=__int_as_float(i0.y), n1=__int_as_float(i1.y);
    float n2=__int_as_float(i2.y), n3=__int_as_float(i3.y);
    acc[0]=fmaf(n0,bflo(d0.x),acc[0]); acc[1]=fmaf(n0,bfhi(d0.x),acc[1]);
    acc[2]=fmaf(n0,bflo(d0.y),acc[2]); acc[3]=fmaf(n0,bfhi(d0.y),acc[3]);
    acc[4]=fmaf(n0,bflo(d0.z),acc[4]); acc[5]=fmaf(n0,bfhi(d0.z),acc[5]);
    acc[0]=fmaf(n1,bflo(d1.x),acc[0]); acc[1]=fmaf(n1,bfhi(d1.x),acc[1]);
    acc[2]=fmaf(n1,bflo(d1.y),acc[2]); acc[3]=fmaf(n1,bfhi(d1.y),acc[3]);
    acc[4]=fmaf(n1,bflo(d1.z),acc[4]); acc[5]=fmaf(n1,bfhi(d1.z),acc[5]);
    acc[0]=fmaf(n2,bflo(d2.x),acc[0]); acc[1]=fmaf(n2,bfhi(d2.x),acc[1]);
    acc[2]=fmaf(n2,bflo(d2.y),acc[2]); acc[3]=fmaf(n2,bfhi(d2.y),acc[3]);
    acc[4]=fmaf(n2,bflo(d2.z),acc[4]); acc[5]=fmaf(n2,bfhi(d2.z),acc[5]);
    acc[0]=fmaf(n3,bflo(d3.x),acc[0]); acc[1]=fmaf(n3,bfhi(d3.x),acc[1]);
    acc[2]=fmaf(n3,bflo(d3.y),acc[2]); acc[3]=fmaf(n3,bfhi(d3.y),acc[3]);
    acc[4]=fmaf(n3,bflo(d3.z),acc[4]); acc[5]=fmaf(n3,bfhi(d3.z),acc[5]);
  }
  for(; e<e1; ++e){
    int2 i0=csr[e];
    U3 d0 = *reinterpret_cast<const U3*>(A + (long long)i0.x*144 + 3*f);
    float n0=__int_as_float(i0.y);
    acc[0]=fmaf(n0,bflo(d0.x),acc[0]); acc[1]=fmaf(n0,bfhi(d0.x),acc[1]);
    acc[2]=fmaf(n0,bflo(d0.y),acc[2]); acc[3]=fmaf(n0,bfhi(d0.y),acc[3]);
    acc[4]=fmaf(n0,bflo(d0.z),acc[4]); acc[5]=fmaf(n0,bfhi(d0.z),acc[5]);
  }
  float bb = bias[f], gg = gain[f], be = beta[f];
  const float rn = 1.0f/HID;
#pragma unroll
  for(int t=0;t<TT;t++){
    float val = fmaf(acc[t], dn, bb);    // final *dn fold
    float v = act? val : 0.f;
    float s = v, s2 = v*v;
#pragma unroll
    for(int m=32;m>=1;m>>=1){
      s  += __shfl_xor(s,  m, 64);
      s2 += __shfl_xor(s2, m, 64);
    }
    float mu  = s*rn;
    float var = fmaxf(s2*rn - mu*mu, 0.f);
    float y = (val-mu)*rsqrtf(var+1e-5f)*gg + be;
    y = fmaxf(y, 0.f);
    long long oidx = (long long)wid*(TT*HID) + t*HID + f;
    if(resid) y += resid[oidx];
    if(act) out[oidx] = y;
  }
}

// ---------------- fused GRU (6 steps) + classifier ----------------
// block: 64 nodes, 384 threads = 6 waves. Wave wv owns 8 features (f0=wv*8), lane = node.
// h/x transposed in LDS [48][65] (conflict-free). Weights via wave-uniform s_load from Wg.
__global__ __launch_bounds__(384) void k_gruF(const float* __restrict__ X,  // h2 [n][t][48]
                                              const float* __restrict__ Wg,
                                              const float* __restrict__ bih, const float* __restrict__ bhh,
                                              const float* __restrict__ Wc1, const float* __restrict__ bc1,
                                              const float* __restrict__ Wc2, const float* __restrict__ bc2,
                                              float* __restrict__ out){
  __shared__ float xbuf[48*LR];
  __shared__ float hbuf[48*LR];
  int tid = threadIdx.x;
  int wv = __builtin_amdgcn_readfirstlane(tid>>6);   // 0..5, uniform
  int lane = tid & 63;
  int f0 = wv*8;
  long long nbase = (long long)blockIdx.x*64;

  for(int i=tid;i<48*LR;i+=384) hbuf[i]=0.f;

  float rb[8], zb[8], nbi[8], nbh[8];
#pragma unroll
  for(int j=0;j<8;j++){
    int f=f0+j;
    rb[j]  = bih[f]    + bhh[f];
    zb[j]  = bih[48+f] + bhh[48+f];
    nbi[j] = bih[96+f];
    nbh[j] = bhh[96+f];
  }

  for(int t=0;t<TT;t++){
    // stage x_t transposed: 768 float4-chunks (64 nodes x 12), 2 per thread
#pragma unroll
    for(int i=0;i<2;i++){
      int c = tid + 384*i;
      int nd = c/12, fc = c - nd*12;
      long long gn = nbase + nd; if(gn>NN-1) gn=NN-1;
      float4 xv = *reinterpret_cast<const float4*>(X + gn*(TT*HID) + t*HID + fc*4);
      int base = (fc*4)*LR + nd;
      xbuf[base]      = xv.x;
      xbuf[base+LR]   = xv.y;
      xbuf[base+2*LR] = xv.z;
      xbuf[base+3*LR] = xv.w;
    }
    __syncthreads();   // xbuf + hbuf ready

    float ra[8],za[8],ia[8],ha[8];
#pragma unroll
    for(int j=0;j<8;j++){ ra[j]=za[j]=ia[j]=ha[j]=0.f; }

#pragma unroll 2
    for(int k=0;k<48;k++){
      const float* wp = Wg + ((wv*48 + k)*48);   // uniform -> s_load
      float ws[48];
#pragma unroll
      for(int q=0;q<48;q++) ws[q]=wp[q];
      float xk = xbuf[k*LR+lane];
      float hk = hbuf[k*LR+lane];
#pragma unroll
      for(int j=0;j<8;j++){
        ra[j]=fmaf(xk,ws[j],   ra[j]); ra[j]=fmaf(hk,ws[24+j],ra[j]);
        za[j]=fmaf(xk,ws[8+j], za[j]); za[j]=fmaf(hk,ws[32+j],za[j]);
        ia[j]=fmaf(xk,ws[16+j],ia[j]); ha[j]=fmaf(hk,ws[40+j],ha[j]);
      }
    }

    float hn[8];
#pragma unroll
    for(int j=0;j<8;j++){
      float r  = sigmoidf_(ra[j]+rb[j]);
      float zg = sigmoidf_(za[j]+zb[j]);
      float ng = tanhf_(ia[j]+nbi[j] + r*(ha[j]+nbh[j]));
      hn[j] = (1.f-zg)*ng + zg*hbuf[(f0+j)*LR+lane];
    }
    __syncthreads();   // all reads done before overwrite
#pragma unroll
    for(int j=0;j<8;j++) hbuf[(f0+j)*LR+lane] = hn[j];
  }
  __syncthreads();     // final h ready

  // classifier epilogue: wave 0 covers the block's 64 nodes
  if(wv==0){
    long long gn = nbase + lane;
    if(gn<NN){
      float hv[24];
#pragma unroll
      for(int j=0;j<24;j++) hv[j]=bc1[j];
      for(int k=0;k<HID;k++){
        float xk = hbuf[k*LR+lane];
        const float* wr = Wc1 + k*24;   // uniform -> s_load
#pragma unroll
        for(int j=0;j<24;j++) hv[j] = fmaf(xk, wr[j], hv[j]);
      }
      float l0=bc2[0], l1=bc2[1];
#pragma unroll
      for(int j=0;j<24;j++){
        float a = fmaxf(hv[j],0.f);
        l0 = fmaf(a, Wc2[2*j],   l0);
        l1 = fmaf(a, Wc2[2*j+1], l1);
      }
      reinterpret_cast<float2*>(out)[gn] = make_float2(l0,l1);
    }
  }
}

static inline size_t al256(size_t x){ return (x+255)&~(size_t)255; }

extern "C" void kernel_launch(void* const* d_in, const int* in_sizes, int n_in,
                              void* d_out, int out_size, void* d_ws, size_t ws_size,
                              hipStream_t stream){
  const float* x_seq=(const float*)d_in[0];
  const int*   ei   =(const int*)d_in[1];
  const float* ew   =(const float*)d_in[2];
  const float* W0=(const float*)d_in[3];  const float* b0=(const float*)d_in[4];
  const float* g0=(const float*)d_in[5];  const float* be0=(const float*)d_in[6];
  const float* W1=(const float*)d_in[7];  const float* b1=(const float*)d_in[8];
  const float* g1=(const float*)d_in[9];  const float* be1=(const float*)d_in[10];
  const float* Wih=(const float*)d_in[11];const float* Whh=(const float*)d_in[12];
  const float* bih=(const float*)d_in[13];const float* bhh=(const float*)d_in[14];
  const float* Wc1=(const float*)d_in[15];const float* bc1=(const float*)d_in[16];
  const float* Wc2=(const float*)d_in[17];const float* bc2=(const float*)d_in[18];
  float* outp=(float*)d_out;

  char* p=(char*)d_ws; size_t off=0;
  auto alloc=[&](size_t bytes)->void*{ void* r=p+off; off=al256(off+bytes); return r; };
  float* dis    =(float*)alloc((size_t)NN*4);
  int*   cnt    =(int*)  alloc((size_t)NN*4);
  int*   offs   =(int*)  alloc((size_t)(NN+1)*4);
  int*   bsum   =(int*)  alloc((size_t)NB*4);
  int*   bpre   =(int*)  alloc((size_t)NB*4);
  int*   pos    =(int*)  alloc((size_t)NE*4);
  int2*  csr    =(int2*) alloc((size_t)NE*8);
  float* Wg     =(float*)alloc((size_t)6*48*48*4);
  unsigned* A   =(unsigned*)alloc((size_t)NN*576 + 1024);   // bf16 [n][f][t6], 576B/row
  float* h1     =(float*)alloc((size_t)NN*TT*HID*4);
  float* h2     =(float*)alloc((size_t)NN*TT*HID*4);

  const int GN=(NN+255)/256, GE=(NE+255)/256;
  const int GMM=(NN+63)/64;              // 64 nodes/block, 4 waves (feature slices)
  const int GAGG=(NN*64+255)/256;        // 1 wave/node
  const int GGRU=(NN+63)/64;             // 64 nodes/block, 6 waves

  k_setup  <<<GN,256,0,stream>>>(cnt,Wih,Whh,Wg);
  k_cnt    <<<GE,256,0,stream>>>(ei,cnt,pos);
  k_partA  <<<NB,256,0,stream>>>(cnt,bsum);
  k_midB   <<<1,256,0,stream>>>(bsum,bpre,offs);
  k_offsC  <<<NB,256,0,stream>>>(cnt,bpre,offs);
  k_scatter<<<GE,256,0,stream>>>(ei,ew,offs,pos,csr);
  k_deg    <<<GN,256,0,stream>>>(csr,offs,dis);
  k_normE  <<<GE,256,0,stream>>>(csr,dis);

  // layer 0
  k_mm0<<<GMM,256,0,stream>>>(x_seq, W0, A);
  k_agg<<<GAGG,256,0,stream>>>(A,b0,g0,be0,nullptr,h1,offs,csr,dis);
  // layer 1 (residual = h1)
  k_mm1<<<GMM,256,0,stream>>>(h1, W1, A);
  k_agg<<<GAGG,256,0,stream>>>(A,b1,g1,be1,h1,h2,offs,csr,dis);
  // fused GRU (6 steps) + classifier
  k_gruF<<<GGRU,384,0,stream>>>(h2, Wg, bih,bhh, Wc1,bc1,Wc2,bc2, outp);
}